// Round 9
// baseline (249.425 us; speedup 1.0000x reference)
//
#include <hip/hip_runtime.h>

// Quantum circuit sim: 12 wires, DIM=4096, 3 layers, batch=512, fp32.
// R9: ZERO-BARRIER single-wave blocks. R3/R8 proved TLP does nothing; the
// residual ~13us is the barrier-phased structure itself. A 64-thread block
// is ONE wave -> wave-synchronous LDS (in-order DS pipe + lgkmcnt) needs no
// s_barrier ever.
//  - lane L holds amp[k] = psi[(k<<6)|L], k=0..63 (128 VGPRs).
//  - wires 0-5 = k-bits: in-register (R6 v_pk asm core, 8 VOP3P/pair).
//  - one LDS transpose per layer -> wires 6-11 become k-bits.
//  - storage S(i) = 65*i[5:0] + i[11:6] (float2): all four access phases are
//    base-VGPR + compile-time immediates; P2-write/transpose-read are
//    conflict-free, P1-write/gather-read 4-way (1.58x, acceptable).
//  - CNOT chain = Gray map perm(i)=i^(i>>1), folded into the layer-boundary
//    gather; layer-3 perm folded into measurement weights via inverse-Gray.
//  - 2 waves/CU (2 SIMDs idle) is the price; barrier stalls were costlier.

namespace {

typedef float v2f __attribute__((ext_vector_type(2)));

constexpr int N_WIRES = 12;
constexpr int DIM     = 1 << N_WIRES;   // 4096
constexpr int PER     = 64;             // amps per lane
constexpr int NG      = 36;

// invGray6: prefix-xor from MSB (6-bit)
__host__ __device__ constexpr int ig6(int x) {
    int y = x; y ^= y >> 1; y ^= y >> 2; y ^= y >> 4; return y & 63;
}

// ---- Packed complex helpers. v2f = (re, im) in a VGPR pair.
// d = u * p:
//   inst1: d.lo = p.re*u.re          d.hi = p.im*u.re
//   inst2: d.lo += p.im*(-u.im)      d.hi += p.re*u.im
__device__ __forceinline__ v2f cmul(v2f u, v2f p) {
    v2f d;
    asm("v_pk_mul_f32 %0, %1, %2 op_sel_hi:[1,0]"
        : "=v"(d) : "v"(p), "v"(u));
    asm("v_pk_fma_f32 %0, %1, %2, %0 op_sel:[1,1,0] op_sel_hi:[0,1,1] neg_lo:[0,1,0]"
        : "+v"(d) : "v"(p), "v"(u));
    return d;
}
// d += u * p
__device__ __forceinline__ void cfma(v2f& d, v2f u, v2f p) {
    asm("v_pk_fma_f32 %0, %1, %2, %0 op_sel_hi:[1,0,1]"
        : "+v"(d) : "v"(p), "v"(u));
    asm("v_pk_fma_f32 %0, %1, %2, %0 op_sel:[1,1,0] op_sel_hi:[0,1,1] neg_lo:[0,1,0]"
        : "+v"(d) : "v"(p), "v"(u));
}

__global__ __launch_bounds__(64, 1)
void qcirc_kernel(const float* __restrict__ state,
                  const float* __restrict__ weights,
                  const float* __restrict__ head_w,
                  const float* __restrict__ head_b,
                  float* __restrict__ out)
{
    __shared__ __align__(16) v2f buf[65 * 64];      // S(i)=65*lo+hi, 33.3 KB
    __shared__ __align__(16) v2f Um[NG][4];

    const int L = threadIdx.x;                      // lane, 6 bits
    const int b = blockIdx.x;

    // ---- 36 gate matrices (lanes 0-35). U = RZ(c)RY(b)RX(a); SU(2):
    // U = [[u00, -conj(u10)], [u10, conj(u00)]].
    if (L < NG) {
        const float* wp = weights + L * 3;
        float ha = 0.5f * wp[0], hb = 0.5f * wp[1], hc = 0.5f * wp[2];
        float ca = cosf(ha), sa = sinf(ha);
        float cb = cosf(hb), sb = sinf(hb);
        float ecr = cosf(hc), eci = -sinf(hc);      // e^{-i c/2}
        float t0 = cb * ca, t1 = sb * sa, t2 = sb * ca, t3 = cb * sa;
        float u00r =  ecr * t0 - eci * t1;
        float u00i =  ecr * t1 + eci * t0;
        float u10r =  ecr * t2 - eci * t3;
        float u10i = -ecr * t3 - eci * t2;
        Um[L][0] = (v2f){ u00r,  u00i};             // u00
        Um[L][1] = (v2f){-u10r,  u10i};             // u01 = -conj(u10)
        Um[L][2] = (v2f){ u10r,  u10i};             // u10
        Um[L][3] = (v2f){ u00r, -u00i};             // u11 = conj(u00)
    }

    // ---- Initial load, phase-1 layout: amp[k] = state[(k<<6)|L] (coalesced).
    v2f amp[PER];
    {
        const float* sp = state + (size_t)b * DIM + L;
        #pragma unroll
        for (int k = 0; k < PER; ++k)
            amp[k] = (v2f){sp[k << 6], 0.f};
    }

    // ---- Gather bases (CNOT Gray perm), runtime parts.
    const int gL  = L ^ (L >> 1);                   // gray6(L)
    const int gb0 = 65 * gL;                        // k even
    const int gb1 = 65 * (gL ^ 32);                 // k odd (j bit5 ^= k&1)

    // Um visible to all lanes (single wave: waitcnt suffices, no barrier)
    asm volatile("s_waitcnt lgkmcnt(0)" ::: "memory");

    int gi = 0;                                     // gate index 0..35
    #pragma unroll 1
    for (int l = 0; l < 3; ++l) {
        #pragma unroll 1
        for (int rep = 0; rep < 2; ++rep) {
            // 6 gates on k-bits 5..0 (rep0: wires 0-5; rep1: wires 6-11)
            #pragma unroll
            for (int gg = 0; gg < 6; ++gg) {
                const v2f u00 = Um[gi + gg][0];
                const v2f u01 = Um[gi + gg][1];
                const v2f u10 = Um[gi + gg][2];
                const v2f u11 = Um[gi + gg][3];
                const int st = 32 >> gg;
                #pragma unroll
                for (int k0 = 0; k0 < PER; ++k0) {
                    if (k0 & st) continue;          // static under full unroll
                    const int k1 = k0 | st;
                    const v2f p = amp[k0], q = amp[k1];
                    v2f np = cmul(u00, p); cfma(np, u01, q);
                    v2f nq = cmul(u10, p); cfma(nq, u11, q);
                    amp[k0] = np;
                    amp[k1] = nq;
                }
            }
            gi += 6;
            if (rep == 0) {
                // P1-write: element (k<<6)|L at S = 65L + k (imm 8k)
                #pragma unroll
                for (int k = 0; k < PER; ++k) buf[65 * L + k] = amp[k];
                asm volatile("s_waitcnt lgkmcnt(0)" ::: "memory");
                // transpose-read: element (L<<6)|k at S = 65k + L (imm 520k)
                #pragma unroll
                for (int k = 0; k < PER; ++k) amp[k] = buf[L + 65 * k];
            }
        }
        if (l < 2) {
            // P2-write: element (L<<6)|k at S = 65k + L — exactly the slots
            // THIS lane read in the transpose (per-lane RAW only, safe).
            #pragma unroll
            for (int k = 0; k < PER; ++k) buf[L + 65 * k] = amp[k];
            asm volatile("s_waitcnt lgkmcnt(0)" ::: "memory");
            // CNOT gather into phase-1: amp[k] = psi[gray12((k<<6)|L)],
            // addr = 65*(gL ^ ((k&1)<<5)) + gray6(k)
            #pragma unroll
            for (int k = 0; k < PER; ++k) {
                const int gk = (k ^ (k >> 1)) & 63; // static
                amp[k] = buf[((k & 1) ? gb1 : gb0) + gk];
            }
            asm volatile("s_waitcnt lgkmcnt(0)" ::: "memory");
        }
    }

    // ---- Measurement. Regs: phase-2 of layer 3 = pre-final-CNOT state at
    // j = (L<<6)|k. Logical m = invGray12(j): m[11:6] = invGray6(L),
    // m[5:0] = invGray6(k) ^ (parity(L)*63). Weight c_m = chi_L + s*lowsum_k
    // (flip of all 6 low bits just negates the low sum).
    // acc_L = chi_L * P + s * Q,  P = sum p_k,  Q = sum lowsum_k * p_k,
    // Q = sum_w hw[6+w] * T_w with static per-k signs from invGray6(k).
    float hw[N_WIRES];
    #pragma unroll
    for (int w = 0; w < N_WIRES; ++w) hw[w] = head_w[w];

    float P = 0.f, T0 = 0.f, T1 = 0.f, T2 = 0.f, T3 = 0.f, T4 = 0.f, T5 = 0.f;
    #pragma unroll
    for (int k = 0; k < PER; ++k) {
        const float p = amp[k].x * amp[k].x + amp[k].y * amp[k].y;
        P += p;
        constexpr auto m = 0;  (void)m;
        const int mg = ig6(k);                      // static
        if (mg & 32) T0 -= p; else T0 += p;         // wire 6  <- m bit 5
        if (mg & 16) T1 -= p; else T1 += p;         // wire 7
        if (mg &  8) T2 -= p; else T2 += p;         // wire 8
        if (mg &  4) T3 -= p; else T3 += p;         // wire 9
        if (mg &  2) T4 -= p; else T4 += p;         // wire 10
        if (mg &  1) T5 -= p; else T5 += p;         // wire 11
    }
    float Q = hw[6] * T0 + hw[7] * T1 + hw[8] * T2
            + hw[9] * T3 + hw[10] * T4 + hw[11] * T5;

    int iL = L; iL ^= iL >> 1; iL ^= iL >> 2; iL ^= iL >> 4;  // invGray6(L)
    float chi = 0.f;
    #pragma unroll
    for (int w = 0; w < 6; ++w)
        chi += ((iL >> (5 - w)) & 1) ? -hw[w] : hw[w];

    float acc = chi * P + ((__popc(L) & 1) ? -Q : Q);

    #pragma unroll
    for (int off = 32; off > 0; off >>= 1)
        acc += __shfl_down(acc, off, 64);
    if (L == 0) out[b] = acc + head_b[0];
}

} // namespace

extern "C" void kernel_launch(void* const* d_in, const int* in_sizes, int n_in,
                              void* d_out, int out_size, void* d_ws, size_t ws_size,
                              hipStream_t stream)
{
    const float* state   = (const float*)d_in[0];  // (B, 4096) fp32
    const float* weights = (const float*)d_in[1];  // (3, 12, 3) fp32
    const float* head_w  = (const float*)d_in[2];  // (1, 12) fp32
    const float* head_b  = (const float*)d_in[3];  // (1,) fp32
    float* out = (float*)d_out;                    // (B,) fp32

    const int batch = in_sizes[0] / DIM;           // 512
    qcirc_kernel<<<batch, 64, 0, stream>>>(state, weights, head_w, head_b, out);
}